// Round 1
// baseline (319.993 us; speedup 1.0000x reference)
//
#include <hip/hip_runtime.h>

// TokenMixer: out[n,b,c] = x_pos[n,b,c] * (1 - sigmoid(cos_sim(x_pre[n,b,:], x_pos[n,b,:])))
// N=4096, B=16, C=512 -> 65536 rows of 512 fp32.
//
// V2: persistent waves + 2-deep register double-buffer prefetch.
//   - One wave (64 lanes) per row, 8 rows per wave (grid-stride).
//   - Next row's 4x float4 loads are issued BEFORE the current row's
//     shfl-reduce chain, so HBM loads stay in flight continuously
//     (V1 was latency-bound: loads only in flight at wave birth).
//   - Contiguous partition: lane owns floats [lane*4, lane*4+4) and
//     [256+lane*4, ...) -> each load instr covers a contiguous 1 KiB.
//   - Non-temporal stores: output stream bypasses L2/L3 so it doesn't
//     evict the L3-resident inputs (FETCH_SIZE was already half-absorbed).

typedef float f32x4 __attribute__((ext_vector_type(4)));

constexpr int C_DIM  = 512;
constexpr int ROWS   = 4096 * 16;      // 65536
constexpr int BLOCKS = 2048;           // 8 blocks/CU on 256 CUs
constexpr int WAVES  = BLOCKS * 4;     // 8192 waves
constexpr int ITERS  = ROWS / WAVES;   // 8 rows per wave

__global__ __launch_bounds__(256, 8) void tokenmixer_kernel(
    const float* __restrict__ pre,
    const float* __restrict__ pos,
    float* __restrict__ out)
{
    const int wave = (int)((blockIdx.x * 256u + threadIdx.x) >> 6);
    const int lane = (int)(threadIdx.x & 63u);
    const size_t lo = (size_t)(lane * 4);

    int row = wave;
    size_t base = (size_t)row * C_DIM + lo;

    // prime the pipeline: row 0 for this wave
    f32x4 pA = *(const f32x4*)(pre + base);
    f32x4 pB = *(const f32x4*)(pre + base + 256);
    f32x4 qA = *(const f32x4*)(pos + base);
    f32x4 qB = *(const f32x4*)(pos + base + 256);

    #pragma unroll 1
    for (int it = 0; it < ITERS; ++it) {
        // ---- prefetch next row (issued before the dependent reduce) ----
        // Last iteration: re-load row `wave` (L3-hot, uniform, branch-free).
        const int nrow = (it + 1 < ITERS) ? (row + WAVES) : wave;
        const size_t nb = (size_t)nrow * C_DIM + lo;
        f32x4 npA = *(const f32x4*)(pre + nb);
        f32x4 npB = *(const f32x4*)(pre + nb + 256);
        f32x4 nqA = *(const f32x4*)(pos + nb);
        f32x4 nqB = *(const f32x4*)(pos + nb + 256);

        // ---- per-lane partial sums (current row) ----
        float s_pre = 0.f, s_pos = 0.f, dot = 0.f;
        #pragma unroll
        for (int i = 0; i < 4; ++i) {
            s_pre = fmaf(pA[i], pA[i], s_pre);
            s_pre = fmaf(pB[i], pB[i], s_pre);
            s_pos = fmaf(qA[i], qA[i], s_pos);
            s_pos = fmaf(qB[i], qB[i], s_pos);
            dot   = fmaf(pA[i], qA[i], dot);
            dot   = fmaf(pB[i], qB[i], dot);
        }

        // ---- 64-lane butterfly reduction (3 values) ----
        #pragma unroll
        for (int m = 1; m < 64; m <<= 1) {
            s_pre += __shfl_xor(s_pre, m, 64);
            s_pos += __shfl_xor(s_pos, m, 64);
            dot   += __shfl_xor(dot,   m, 64);
        }

        const float n_pre = fmaxf(sqrtf(s_pre), 1e-12f);
        const float n_pos = fmaxf(sqrtf(s_pos), 1e-12f);
        const float cosv  = dot / (n_pre * n_pos);
        // 1 - sigmoid(x) = 1 / (1 + e^x)
        const float w = 1.0f / (1.0f + __expf(cosv));

        const f32x4 oA = qA * w;
        const f32x4 oB = qB * w;
        __builtin_nontemporal_store(oA, (f32x4*)(out + base));
        __builtin_nontemporal_store(oB, (f32x4*)(out + base + 256));

        // ---- rotate buffers ----
        row  = nrow;
        base = nb;
        pA = npA; pB = npB; qA = nqA; qB = nqB;
    }
}

extern "C" void kernel_launch(void* const* d_in, const int* in_sizes, int n_in,
                              void* d_out, int out_size, void* d_ws, size_t ws_size,
                              hipStream_t stream) {
    const float* pre = (const float*)d_in[0];
    const float* pos = (const float*)d_in[1];
    float* out = (float*)d_out;

    tokenmixer_kernel<<<BLOCKS, 256, 0, stream>>>(pre, pos, out);
}

// Round 2
// 305.968 us; speedup vs baseline: 1.0458x; 1.0458x over previous
//
#include <hip/hip_runtime.h>

// TokenMixer: out[n,b,c] = x_pos[n,b,c] * (1 - sigmoid(cos_sim(x_pre[n,b,:], x_pos[n,b,:])))
// N=4096, B=16, C=512 -> 65536 rows of 512 fp32.
//
// V3: back to non-persistent wave churn (V1's better residency model), but
// each wave processes TWO adjacent rows with all 8 float4 loads issued
// up front:
//   - 8 KB in flight per wave (V1: 4 KB) -> 2x memory-level parallelism,
//     HBM latency amortized over 2 rows.
//   - 6 independent butterfly-reduce values (3 per row) interleaved per
//     stage -> DS ops pipeline instead of serializing.
//   - Contiguous lane partition: lane owns floats [lane*4, lane*4+4) and
//     [256+lane*4, ...): each load instruction covers a dense 1 KiB.
//   - Plain stores (V2's nontemporal stores did not reduce FETCH_SIZE).
//   - No tail reload (V2's +16 MB HBM fetch regression).

typedef float f32x4 __attribute__((ext_vector_type(4)));

constexpr int C_DIM = 512;
constexpr int ROWS  = 4096 * 16;   // 65536

__global__ __launch_bounds__(256, 8) void tokenmixer_kernel(
    const float* __restrict__ pre,
    const float* __restrict__ pos,
    float* __restrict__ out)
{
    const int wave = (int)((blockIdx.x * 256u + threadIdx.x) >> 6);  // 0..32767
    const int lane = (int)(threadIdx.x & 63u);

    const size_t b0 = (size_t)(2 * wave) * C_DIM + (size_t)(lane * 4);
    const size_t b1 = b0 + C_DIM;

    // ---- all 8 loads issued before any use: 8 KB/wave in flight ----
    const f32x4 pA0 = *(const f32x4*)(pre + b0);
    const f32x4 pB0 = *(const f32x4*)(pre + b0 + 256);
    const f32x4 pA1 = *(const f32x4*)(pre + b1);
    const f32x4 pB1 = *(const f32x4*)(pre + b1 + 256);
    const f32x4 qA0 = *(const f32x4*)(pos + b0);
    const f32x4 qB0 = *(const f32x4*)(pos + b0 + 256);
    const f32x4 qA1 = *(const f32x4*)(pos + b1);
    const f32x4 qB1 = *(const f32x4*)(pos + b1 + 256);

    // ---- per-lane partials, 2 rows x 3 values ----
    float sp0 = 0.f, sq0 = 0.f, d0 = 0.f;
    float sp1 = 0.f, sq1 = 0.f, d1 = 0.f;
#pragma unroll
    for (int i = 0; i < 4; ++i) {
        sp0 = fmaf(pA0[i], pA0[i], sp0);
        sp0 = fmaf(pB0[i], pB0[i], sp0);
        sq0 = fmaf(qA0[i], qA0[i], sq0);
        sq0 = fmaf(qB0[i], qB0[i], sq0);
        d0  = fmaf(pA0[i], qA0[i], d0);
        d0  = fmaf(pB0[i], qB0[i], d0);

        sp1 = fmaf(pA1[i], pA1[i], sp1);
        sp1 = fmaf(pB1[i], pB1[i], sp1);
        sq1 = fmaf(qA1[i], qA1[i], sq1);
        sq1 = fmaf(qB1[i], qB1[i], sq1);
        d1  = fmaf(pA1[i], qA1[i], d1);
        d1  = fmaf(pB1[i], qB1[i], d1);
    }

    // ---- 64-lane butterfly, 6 independent values per stage ----
#pragma unroll
    for (int m = 1; m < 64; m <<= 1) {
        sp0 += __shfl_xor(sp0, m, 64);
        sq0 += __shfl_xor(sq0, m, 64);
        d0  += __shfl_xor(d0,  m, 64);
        sp1 += __shfl_xor(sp1, m, 64);
        sq1 += __shfl_xor(sq1, m, 64);
        d1  += __shfl_xor(d1,  m, 64);
    }

    const float np0 = fmaxf(sqrtf(sp0), 1e-12f);
    const float nq0 = fmaxf(sqrtf(sq0), 1e-12f);
    const float np1 = fmaxf(sqrtf(sp1), 1e-12f);
    const float nq1 = fmaxf(sqrtf(sq1), 1e-12f);
    const float c0  = d0 / (np0 * nq0);
    const float c1  = d1 / (np1 * nq1);
    // 1 - sigmoid(x) = 1 / (1 + e^x)
    const float w0 = 1.0f / (1.0f + __expf(c0));
    const float w1 = 1.0f / (1.0f + __expf(c1));

    *(f32x4*)(out + b0)       = qA0 * w0;
    *(f32x4*)(out + b0 + 256) = qB0 * w0;
    *(f32x4*)(out + b1)       = qA1 * w1;
    *(f32x4*)(out + b1 + 256) = qB1 * w1;
}

extern "C" void kernel_launch(void* const* d_in, const int* in_sizes, int n_in,
                              void* d_out, int out_size, void* d_ws, size_t ws_size,
                              hipStream_t stream) {
    const float* pre = (const float*)d_in[0];
    const float* pos = (const float*)d_in[1];
    float* out = (float*)d_out;

    // 2 rows per wave, 4 waves per block -> 8 rows per block
    const int blocks = ROWS / 8;   // 8192
    tokenmixer_kernel<<<blocks, 256, 0, stream>>>(pre, pos, out);
}

// Round 4
// 304.204 us; speedup vs baseline: 1.0519x; 1.0058x over previous
//
#include <hip/hip_runtime.h>

// TokenMixer: out[n,b,c] = x_pos[n,b,c] * (1 - sigmoid(cos_sim(x_pre[n,b,:], x_pos[n,b,:])))
// N=4096, B=16, C=512 -> 65536 rows of 512 fp32.
//
// V4b: same theory as V4 (round 3 bench was an infra failure, not a verdict),
// with a hardened schedule pin.
//   Post-mortem of V1/V3: VGPR_Count 16/24 -> compiler fissioned multi-row
//   schedules back to row-at-a-time, so only ~2 loads in flight per wave;
//   kernel is latency-bound (VALUBusy ~12%, HBM ~30%, zero LDS conflicts).
//   Fix: all 8 float4 loads (2 rows x {pre,pos} x 2 halves) issued up front,
//   then a per-value liveness pin (asm "v" inputs) forces all 8 destinations
//   to be simultaneously materialized -> 8 KB/wave outstanding, ~5-7x the
//   aggregate bytes-in-flight per CU. launch_bounds(256,8) caps VGPR at 64
//   (need ~50) -> no spill, occupancy preserved.

typedef float f32x4 __attribute__((ext_vector_type(4)));

constexpr int C_DIM = 512;
constexpr int ROWS  = 4096 * 16;   // 65536

__global__ __launch_bounds__(256, 8) void tokenmixer_kernel(
    const float* __restrict__ pre,
    const float* __restrict__ pos,
    float* __restrict__ out)
{
    const int wave = (int)((blockIdx.x * 256u + threadIdx.x) >> 6);  // 0..32767
    const int lane = (int)(threadIdx.x & 63u);

    const size_t b0 = (size_t)(2 * wave) * C_DIM + (size_t)(lane * 4);
    const size_t b1 = b0 + C_DIM;

    // ---- all 8 loads issued before any use ----
    f32x4 pA0 = *(const f32x4*)(pre + b0);
    f32x4 pB0 = *(const f32x4*)(pre + b0 + 256);
    f32x4 qA0 = *(const f32x4*)(pos + b0);
    f32x4 qB0 = *(const f32x4*)(pos + b0 + 256);
    f32x4 pA1 = *(const f32x4*)(pre + b1);
    f32x4 pB1 = *(const f32x4*)(pre + b1 + 256);
    f32x4 qA1 = *(const f32x4*)(pos + b1);
    f32x4 qB1 = *(const f32x4*)(pos + b1 + 256);

    // ---- liveness pin (guide rule #17): all 8 vectors must be in registers
    //      here, so the compiler cannot fission the loads row-at-a-time ----
    asm volatile("" :: "v"(pA0), "v"(pB0), "v"(qA0), "v"(qB0),
                       "v"(pA1), "v"(pB1), "v"(qA1), "v"(qB1));

    // ---- per-lane partials, 2 rows x 3 values ----
    float sp0 = 0.f, sq0 = 0.f, d0 = 0.f;
    float sp1 = 0.f, sq1 = 0.f, d1 = 0.f;
#pragma unroll
    for (int i = 0; i < 4; ++i) {
        sp0 = fmaf(pA0[i], pA0[i], sp0);
        sp0 = fmaf(pB0[i], pB0[i], sp0);
        sq0 = fmaf(qA0[i], qA0[i], sq0);
        sq0 = fmaf(qB0[i], qB0[i], sq0);
        d0  = fmaf(pA0[i], qA0[i], d0);
        d0  = fmaf(pB0[i], qB0[i], d0);

        sp1 = fmaf(pA1[i], pA1[i], sp1);
        sp1 = fmaf(pB1[i], pB1[i], sp1);
        sq1 = fmaf(qA1[i], qA1[i], sq1);
        sq1 = fmaf(qB1[i], qB1[i], sq1);
        d1  = fmaf(pA1[i], qA1[i], d1);
        d1  = fmaf(pB1[i], qB1[i], d1);
    }

    // ---- 64-lane butterfly, 6 independent values per stage ----
#pragma unroll
    for (int m = 1; m < 64; m <<= 1) {
        sp0 += __shfl_xor(sp0, m, 64);
        sq0 += __shfl_xor(sq0, m, 64);
        d0  += __shfl_xor(d0,  m, 64);
        sp1 += __shfl_xor(sp1, m, 64);
        sq1 += __shfl_xor(sq1, m, 64);
        d1  += __shfl_xor(d1,  m, 64);
    }

    const float np0 = fmaxf(sqrtf(sp0), 1e-12f);
    const float nq0 = fmaxf(sqrtf(sq0), 1e-12f);
    const float np1 = fmaxf(sqrtf(sp1), 1e-12f);
    const float nq1 = fmaxf(sqrtf(sq1), 1e-12f);
    const float c0  = d0 / (np0 * nq0);
    const float c1  = d1 / (np1 * nq1);
    // 1 - sigmoid(x) = 1 / (1 + e^x)
    const float w0 = 1.0f / (1.0f + __expf(c0));
    const float w1 = 1.0f / (1.0f + __expf(c1));

    *(f32x4*)(out + b0)       = qA0 * w0;
    *(f32x4*)(out + b0 + 256) = qB0 * w0;
    *(f32x4*)(out + b1)       = qA1 * w1;
    *(f32x4*)(out + b1 + 256) = qB1 * w1;
}

extern "C" void kernel_launch(void* const* d_in, const int* in_sizes, int n_in,
                              void* d_out, int out_size, void* d_ws, size_t ws_size,
                              hipStream_t stream) {
    const float* pre = (const float*)d_in[0];
    const float* pos = (const float*)d_in[1];
    float* out = (float*)d_out;

    // 2 rows per wave, 4 waves per block -> 8 rows per block
    const int blocks = ROWS / 8;   // 8192
    tokenmixer_kernel<<<blocks, 256, 0, stream>>>(pre, pos, out);
}